// Round 2
// baseline (397.972 us; speedup 1.0000x reference)
//
#include <hip/hip_runtime.h>
#include <hip/hip_bf16.h>

#define Bn 1024
#define Lr 320
#define Dd 128
#define Ee 8
#define Pp 96
#define TK 64

__device__ __forceinline__ float cdf_f(float v) {
    return 0.5f * (1.0f + erff(v * 0.70710678118654752f));
}
__device__ __forceinline__ float softplus_f(float x) {
    return fmaxf(x, 0.0f) + log1pf(expf(-fabsf(x)));
}

// One block per b: compute g[b,:], logits, noisy top-3, gates, prob; atomics for load/importance.
__global__ __launch_bounds__(256) void gating_kernel(
    const float* __restrict__ x, const float* __restrict__ noise,
    const float* __restrict__ start_w, const float* __restrict__ start_b,
    const float* __restrict__ w_gate, const float* __restrict__ w_noise,
    float* __restrict__ accum /* [0..7]=load, [8..15]=importance */,
    float* __restrict__ gates_out /* Bn*Ee */)
{
    __shared__ float g_s[Lr];
    __shared__ float pc_s[256], pn_s[256];
    __shared__ float clean_s[Ee], std_s[Ee], noisy_s[Ee], gate_s[Ee];
    __shared__ float thr_s[2];

    const int b    = blockIdx.x;
    const int tid  = threadIdx.x;
    const int lane = tid & 63;
    const int wv   = tid >> 6;
    const int hl   = lane & 31;

    const float4 swv = ((const float4*)start_w)[hl];
    const float  sb  = start_b[0];
    const float* xb  = x + (size_t)b * Lr * Dd;

    // g[row] = dot(x[b,row,:], start_w) + sb.  Wave handles 2 rows/iter (1 KB coalesced).
    for (int p = wv; p < Lr / 2; p += 4) {
        const int row = 2 * p + (lane >> 5);
        const float4 xv = ((const float4*)(xb + row * Dd))[hl];
        float part = xv.x * swv.x + xv.y * swv.y + xv.z * swv.z + xv.w * swv.w;
        #pragma unroll
        for (int off = 16; off >= 1; off >>= 1) part += __shfl_xor(part, off);
        if (hl == 0) g_s[row] = part + sb;
    }
    __syncthreads();

    // clean/noise logits: 8 experts x 32 l-slices
    {
        const int e = tid & 7, j = tid >> 3;
        float pc = 0.f, pn = 0.f;
        for (int l = j; l < Lr; l += 32) {
            const float gvv = g_s[l];
            pc += gvv * w_gate[l * Ee + e];
            pn += gvv * w_noise[l * Ee + e];
        }
        pc_s[tid] = pc; pn_s[tid] = pn;
    }
    __syncthreads();
    if (tid < Ee) {
        float c = 0.f, nv = 0.f;
        for (int jj = 0; jj < 32; ++jj) { c += pc_s[tid + 8 * jj]; nv += pn_s[tid + 8 * jj]; }
        const float sdv = softplus_f(nv) + 0.01f;   // NOISE_EPS
        clean_s[tid] = c;
        std_s[tid]   = sdv;
        noisy_s[tid] = c + noise[b * Ee + tid] * sdv;
        gate_s[tid]  = 0.f;
    }
    __syncthreads();
    if (tid == 0) {
        float v[Ee];
        #pragma unroll
        for (int i = 0; i < Ee; ++i) v[i] = noisy_s[i];
        int i0 = -1, i1 = -1;
        float v0 = -INFINITY, v1 = -INFINITY, v2 = -INFINITY;
        for (int i = 0; i < Ee; ++i) if (v[i] > v0) { v0 = v[i]; i0 = i; }
        for (int i = 0; i < Ee; ++i) if (i != i0 && v[i] > v1) { v1 = v[i]; i1 = i; }
        for (int i = 0; i < Ee; ++i) if (i != i0 && i != i1 && v[i] > v2) { v2 = v[i]; }
        const float ex1 = expf(v1 - v0);
        const float den = 1.f + ex1;
        gate_s[i0] = 1.f / den;
        gate_s[i1] = ex1 / den;
        thr_s[0] = v2;   // thr_in  (K+1-th)
        thr_s[1] = v1;   // thr_out (K-th)
    }
    __syncthreads();
    if (tid < Ee) {
        const float gvv = gate_s[tid];
        gates_out[b * Ee + tid] = gvv;
        atomicAdd(&accum[8 + tid], gvv);
        float c = clean_s[tid];
        if (isnan(c)) c = 0.f;
        const float sdv = std_s[tid];
        const float pr = (noisy_s[tid] > thr_s[0]) ? cdf_f((c - thr_s[0]) / sdv)
                                                   : cdf_f((c - thr_s[1]) / sdv);
        atomicAdd(&accum[tid], pr);
    }
}

// One block per b: out[b] (96x128) = W_b^T (96x320) * x[b] (320x128), fp32 LDS-tiled.
__global__ __launch_bounds__(256) void matmul_kernel(
    const float* __restrict__ x, const float* __restrict__ expert_w,
    const float* __restrict__ expert_b, const float* __restrict__ gates,
    float* __restrict__ out)
{
    __shared__ __align__(16) float Xs[TK * Dd];  // 32 KB
    __shared__ __align__(16) float Ws[TK * Pp];  // 24 KB

    const int b   = blockIdx.x;
    const int tid = threadIdx.x;
    const int tx  = tid & 31;   // d / 4
    const int ty  = tid >> 5;   // p / 4 (mod 32)

    // top-2 experts from gate row
    int e0 = 0, e1 = 0; float g0 = 0.f, g1 = 0.f; int cnt = 0;
    #pragma unroll
    for (int e = 0; e < Ee; ++e) {
        const float gv = gates[b * Ee + e];
        if (gv != 0.f) {
            if (cnt == 0) { e0 = e; g0 = gv; }
            else if (cnt == 1) { e1 = e; g1 = gv; }
            ++cnt;
        }
    }

    float acc[12][4];
    #pragma unroll
    for (int i = 0; i < 12; ++i)
        #pragma unroll
        for (int jd = 0; jd < 4; ++jd) acc[i][jd] = 0.f;

    const float* xb = x + (size_t)b * Lr * Dd;
    for (int l0 = 0; l0 < Lr; l0 += TK) {
        __syncthreads();
        // stage X tile (64x128): contiguous, fully coalesced
        {
            const float4* xg = (const float4*)(xb + l0 * Dd);
            float4* xs4 = (float4*)Xs;
            #pragma unroll
            for (int i = 0; i < 8; ++i) xs4[tid + 256 * i] = xg[tid + 256 * i];
        }
        // stage W tile (64x96) = g0*ew[e0] + g1*ew[e1]  (L2-resident)
        {
            const float4* w0g = (const float4*)(expert_w + ((size_t)e0 * Lr + l0) * Pp);
            const float4* w1g = (const float4*)(expert_w + ((size_t)e1 * Lr + l0) * Pp);
            float4* ws4 = (float4*)Ws;
            #pragma unroll
            for (int i = 0; i < 6; ++i) {
                const float4 a = w0g[tid + 256 * i];
                const float4 c = w1g[tid + 256 * i];
                float4 r;
                r.x = g0 * a.x + g1 * c.x; r.y = g0 * a.y + g1 * c.y;
                r.z = g0 * a.z + g1 * c.z; r.w = g0 * a.w + g1 * c.w;
                ws4[tid + 256 * i] = r;
            }
        }
        __syncthreads();
        #pragma unroll 4
        for (int l = 0; l < TK; ++l) {
            const float4 xv  = *(const float4*)&Xs[l * Dd + 4 * tx];
            const float4 wv0 = *(const float4*)&Ws[l * Pp + 4 * ty];
            const float4 wv1 = *(const float4*)&Ws[l * Pp + 4 * ty + 32];
            const float4 wv2 = *(const float4*)&Ws[l * Pp + 4 * ty + 64];
            const float wvs[12] = {wv0.x, wv0.y, wv0.z, wv0.w,
                                   wv1.x, wv1.y, wv1.z, wv1.w,
                                   wv2.x, wv2.y, wv2.z, wv2.w};
            const float xvs[4] = {xv.x, xv.y, xv.z, xv.w};
            #pragma unroll
            for (int i = 0; i < 12; ++i)
                #pragma unroll
                for (int jd = 0; jd < 4; ++jd)
                    acc[i][jd] = fmaf(wvs[i], xvs[jd], acc[i][jd]);
        }
    }

    // epilogue: + gates @ expert_b, fp32 float4 stores
    const float* eb0 = expert_b + (size_t)e0 * Pp * Dd;
    const float* eb1 = expert_b + (size_t)e1 * Pp * Dd;
    #pragma unroll
    for (int i = 0; i < 12; ++i) {
        const int p = 4 * ty + (i & 3) + 32 * (i >> 2);
        const float4 b0 = *(const float4*)(eb0 + p * Dd + 4 * tx);
        const float4 b1 = *(const float4*)(eb1 + p * Dd + 4 * tx);
        float4 r;
        r.x = acc[i][0] + g0 * b0.x + g1 * b1.x;
        r.y = acc[i][1] + g0 * b0.y + g1 * b1.y;
        r.z = acc[i][2] + g0 * b0.z + g1 * b1.z;
        r.w = acc[i][3] + g0 * b0.w + g1 * b1.w;
        *(float4*)(out + ((size_t)b * Pp + p) * Dd + 4 * tx) = r;
    }
}

__global__ void loss_kernel(const float* __restrict__ accum,
                            float* __restrict__ out_scalars)
{
    if (threadIdx.x == 0) {
        float lo[8], im[8];
        #pragma unroll
        for (int i = 0; i < 8; ++i) { lo[i] = accum[i]; im[i] = accum[8 + i]; }
        float ml = 0.f, mi = 0.f;
        #pragma unroll
        for (int i = 0; i < 8; ++i) { ml += lo[i]; mi += im[i]; }
        ml *= 0.125f; mi *= 0.125f;
        float sl = 0.f, si = 0.f;
        #pragma unroll
        for (int i = 0; i < 8; ++i) {
            const float dl = lo[i] - ml, di = im[i] - mi;
            sl += dl * dl; si += di * di;
        }
        const float cvl = (sl / 7.f) / (ml * ml + 1e-10f);
        const float cvi = (si / 7.f) / (mi * mi + 1e-10f);
        const float loss = 0.01f * (cvi + cvl);
        out_scalars[0] = loss;
        out_scalars[1] = 0.0f;
    }
}

extern "C" void kernel_launch(void* const* d_in, const int* in_sizes, int n_in,
                              void* d_out, int out_size, void* d_ws, size_t ws_size,
                              hipStream_t stream)
{
    const float* x        = (const float*)d_in[0];
    // d_in[1] = x_mark_enc (unused by reference)
    const float* noise    = (const float*)d_in[2];
    const float* start_w  = (const float*)d_in[3];
    const float* start_b  = (const float*)d_in[4];
    const float* w_gate   = (const float*)d_in[5];
    const float* w_noise  = (const float*)d_in[6];
    const float* expert_w = (const float*)d_in[7];
    const float* expert_b = (const float*)d_in[8];
    float* out            = (float*)d_out;

    float* accum = (float*)d_ws;         // 16 floats: load[8] + importance[8]
    float* gates = (float*)d_ws + 16;    // Bn*Ee floats

    hipMemsetAsync(accum, 0, 16 * sizeof(float), stream);
    hipLaunchKernelGGL(gating_kernel, dim3(Bn), dim3(256), 0, stream,
                       x, noise, start_w, start_b, w_gate, w_noise, accum, gates);
    hipLaunchKernelGGL(loss_kernel, dim3(1), dim3(64), 0, stream,
                       accum, out + (size_t)Bn * Pp * Dd);
    hipLaunchKernelGGL(matmul_kernel, dim3(Bn), dim3(256), 0, stream,
                       x, expert_w, expert_b, gates, out);
}

// Round 3
// 321.459 us; speedup vs baseline: 1.2380x; 1.2380x over previous
//
#include <hip/hip_runtime.h>
#include <hip/hip_bf16.h>

#define Bn 1024
#define Lr 320
#define Dd 128
#define Ee 8
#define Pp 96

typedef short bf16x8 __attribute__((ext_vector_type(8)));
typedef float f32x4 __attribute__((ext_vector_type(4)));
typedef unsigned short u16;

__device__ __forceinline__ float cdf_f(float v) {
    return 0.5f * (1.0f + erff(v * 0.70710678118654752f));
}
__device__ __forceinline__ float softplus_f(float x) {
    return fmaxf(x, 0.0f) + log1pf(expf(-fabsf(x)));
}
__device__ __forceinline__ u16 f2bf(float f) {
    unsigned int u = __float_as_uint(f);
    return (u16)((u + 0x7fffu + ((u >> 16) & 1u)) >> 16);
}
__device__ __forceinline__ float bf2f(u16 u) {
    return __uint_as_float(((unsigned int)u) << 16);
}

// expert_w fp32 [e][l][p] -> W_t bf16 [e][p][l] (l contiguous). 0.5 MB, L2-resident.
__global__ __launch_bounds__(256) void transpose_w(
    const float* __restrict__ ew, u16* __restrict__ wt)
{
    __shared__ float tile[Pp * 33];
    const int e  = blockIdx.x;       // 0..7
    const int l0 = blockIdx.y * 32;  // 0..288
    const int t  = threadIdx.x;
    #pragma unroll
    for (int i = 0; i < 12; ++i) {
        const int idx = t + 256 * i;            // 0..3071
        const int lp = idx / 96, p = idx - 96 * lp;
        tile[p * 33 + lp] = ew[((size_t)e * Lr + l0 + lp) * Pp + p];
    }
    __syncthreads();
    #pragma unroll
    for (int i = 0; i < 6; ++i) {
        const int g = t + 256 * i;              // 0..1535
        const int p = g >> 4, l2 = (g & 15) * 2;
        const unsigned pk = (unsigned)f2bf(tile[p * 33 + l2]) |
                            ((unsigned)f2bf(tile[p * 33 + l2 + 1]) << 16);
        *(unsigned*)&wt[((size_t)(e * Pp + p)) * Lr + l0 + l2] = pk;
    }
}

// Fused: gating (x read from HBM) + bf16-MFMA GEMM (x re-read from L3, LDS-transposed tiles).
__global__ __launch_bounds__(256, 4) void fused_kernel(
    const float* __restrict__ x, const float* __restrict__ noise,
    const float* __restrict__ start_w, const float* __restrict__ start_b,
    const float* __restrict__ w_gate, const float* __restrict__ w_noise,
    const u16* __restrict__ wt, const float* __restrict__ expert_b,
    float* __restrict__ accum, float* __restrict__ out)
{
    __shared__ float g_s[Lr];
    __shared__ float pc_s[256], pn_s[256];
    __shared__ float cl_s[Ee], sd_s[Ee], ns_s[Ee], gt_s[Ee];
    __shared__ float thr_s[2];
    __shared__ __align__(16) u16 Xs[Dd * 40];  // x^T tile: [d][l' (32, stride 40)]
    __shared__ __align__(16) u16 Ws[Pp * 40];  // W_b^T tile: [p][l' (32, stride 40)]

    const int b    = blockIdx.x;
    const int tid  = threadIdx.x;
    const int lane = tid & 63;
    const int wv   = tid >> 6;
    const int hl   = lane & 31;
    const float* xb = x + (size_t)b * Lr * Dd;

    // ---------- Phase 1: gating (identical math to the verified round-2 kernel) ----------
    {
        const float4 swv = ((const float4*)start_w)[hl];
        const float  sb  = start_b[0];
        for (int p = wv; p < Lr / 2; p += 4) {
            const int row = 2 * p + (lane >> 5);
            const float4 xv = ((const float4*)(xb + row * Dd))[hl];
            float part = xv.x * swv.x + xv.y * swv.y + xv.z * swv.z + xv.w * swv.w;
            #pragma unroll
            for (int off = 16; off >= 1; off >>= 1) part += __shfl_xor(part, off);
            if (hl == 0) g_s[row] = part + sb;
        }
        __syncthreads();
        {
            const int e = tid & 7, j = tid >> 3;
            float pc = 0.f, pn = 0.f;
            for (int l = j; l < Lr; l += 32) {
                const float gvv = g_s[l];
                pc += gvv * w_gate[l * Ee + e];
                pn += gvv * w_noise[l * Ee + e];
            }
            pc_s[tid] = pc; pn_s[tid] = pn;
        }
        __syncthreads();
        if (tid < Ee) {
            float c = 0.f, nv = 0.f;
            for (int jj = 0; jj < 32; ++jj) { c += pc_s[tid + 8 * jj]; nv += pn_s[tid + 8 * jj]; }
            const float sdv = softplus_f(nv) + 0.01f;
            cl_s[tid] = c;
            sd_s[tid] = sdv;
            ns_s[tid] = c + noise[b * Ee + tid] * sdv;
            gt_s[tid] = 0.f;
        }
        __syncthreads();
        if (tid == 0) {
            float v[Ee];
            #pragma unroll
            for (int i = 0; i < Ee; ++i) v[i] = ns_s[i];
            int i0 = -1, i1 = -1;
            float v0 = -INFINITY, v1 = -INFINITY, v2 = -INFINITY;
            for (int i = 0; i < Ee; ++i) if (v[i] > v0) { v0 = v[i]; i0 = i; }
            for (int i = 0; i < Ee; ++i) if (i != i0 && v[i] > v1) { v1 = v[i]; i1 = i; }
            for (int i = 0; i < Ee; ++i) if (i != i0 && i != i1 && v[i] > v2) { v2 = v[i]; }
            const float ex1 = expf(v1 - v0);
            const float den = 1.f + ex1;
            gt_s[i0] = 1.f / den;
            gt_s[i1] = ex1 / den;
            thr_s[0] = v2;
            thr_s[1] = v1;
        }
        __syncthreads();
        if (tid < Ee) {
            const float gvv = gt_s[tid];
            atomicAdd(&accum[8 + tid], gvv);
            float c = cl_s[tid];
            if (isnan(c)) c = 0.f;
            const float sdv = sd_s[tid];
            const float pr = (ns_s[tid] > thr_s[0]) ? cdf_f((c - thr_s[0]) / sdv)
                                                    : cdf_f((c - thr_s[1]) / sdv);
            atomicAdd(&accum[tid], pr);
        }
        __syncthreads();
    }

    // top-2 broadcast (all threads)
    int e0 = 0, e1 = 0; float g0 = 0.f, g1 = 0.f;
    {
        int cnt = 0;
        #pragma unroll
        for (int e = 0; e < Ee; ++e) {
            const float gv = gt_s[e];
            if (gv != 0.f) {
                if (cnt == 0) { e0 = e; g0 = gv; }
                else if (cnt == 1) { e1 = e; g1 = gv; }
                ++cnt;
            }
        }
    }

    // ---------- Phase 2: MFMA GEMM  C[p=96][d=128] = sum_l W_b[l,p] * x[b,l,d] ----------
    const int quad  = lane >> 4;
    const int r16   = lane & 15;
    const int dbase = 32 * wv;          // wave owns d in [32w, 32w+32)
    const int dcol  = tid & 127;        // staging: thread owns one d column
    const int lgrp  = tid >> 7;         // 0/1: l' halves

    f32x4 acc[6][2];
    #pragma unroll
    for (int m = 0; m < 6; ++m)
        #pragma unroll
        for (int n = 0; n < 2; ++n) acc[m][n] = (f32x4){0.f, 0.f, 0.f, 0.f};

    for (int l0 = 0; l0 < Lr; l0 += 32) {
        // stage x^T tile: Xs[d][l'] bf16, pairs packed as b32 writes
        #pragma unroll
        for (int k = 0; k < 8; ++k) {
            const int lp = 16 * lgrp + 2 * k;
            const float a = xb[(size_t)(l0 + lp) * Dd + dcol];
            const float c = xb[(size_t)(l0 + lp + 1) * Dd + dcol];
            ((unsigned*)Xs)[(dcol * 40 + lp) >> 1] =
                (unsigned)f2bf(a) | ((unsigned)f2bf(c) << 16);
        }
        // stage W_b^T tile: Ws[p][l'] = bf16(g0*wt[e0] + g1*wt[e1]), b64 writes
        #pragma unroll
        for (int i = 0; i < 3; ++i) {
            const int g = tid + 256 * i;        // 0..767
            const int p = g >> 3, lq = (g & 7) * 4;
            const ushort4 w0 = *(const ushort4*)&wt[(size_t)(e0 * Pp + p) * Lr + l0 + lq];
            const ushort4 w1 = *(const ushort4*)&wt[(size_t)(e1 * Pp + p) * Lr + l0 + lq];
            ushort4 o;
            o.x = f2bf(g0 * bf2f(w0.x) + g1 * bf2f(w1.x));
            o.y = f2bf(g0 * bf2f(w0.y) + g1 * bf2f(w1.y));
            o.z = f2bf(g0 * bf2f(w0.z) + g1 * bf2f(w1.z));
            o.w = f2bf(g0 * bf2f(w0.w) + g1 * bf2f(w1.w));
            *(ushort4*)&Ws[p * 40 + lq] = o;
        }
        __syncthreads();
        bf16x8 af[6], bfr[2];
        #pragma unroll
        for (int m = 0; m < 6; ++m)
            af[m] = *(const bf16x8*)&Ws[(16 * m + r16) * 40 + 8 * quad];
        #pragma unroll
        for (int n = 0; n < 2; ++n)
            bfr[n] = *(const bf16x8*)&Xs[(dbase + 16 * n + r16) * 40 + 8 * quad];
        #pragma unroll
        for (int m = 0; m < 6; ++m)
            #pragma unroll
            for (int n = 0; n < 2; ++n)
                acc[m][n] = __builtin_amdgcn_mfma_f32_16x16x32_bf16(
                    af[m], bfr[n], acc[m][n], 0, 0, 0);
        __syncthreads();
    }

    // epilogue: + g0*eb[e0] + g1*eb[e1]; fp32 stores
    const float* eb0 = expert_b + (size_t)e0 * Pp * Dd;
    const float* eb1 = expert_b + (size_t)e1 * Pp * Dd;
    #pragma unroll
    for (int m = 0; m < 6; ++m) {
        #pragma unroll
        for (int n = 0; n < 2; ++n) {
            const int d = dbase + 16 * n + r16;
            #pragma unroll
            for (int r = 0; r < 4; ++r) {
                const int p = 16 * m + 4 * quad + r;
                out[((size_t)b * Pp + p) * Dd + d] =
                    acc[m][n][r] + g0 * eb0[p * Dd + d] + g1 * eb1[p * Dd + d];
            }
        }
    }
}

__global__ void loss_kernel(const float* __restrict__ accum,
                            float* __restrict__ out_scalars)
{
    if (threadIdx.x == 0) {
        float lo[8], im[8];
        #pragma unroll
        for (int i = 0; i < 8; ++i) { lo[i] = accum[i]; im[i] = accum[8 + i]; }
        float ml = 0.f, mi = 0.f;
        #pragma unroll
        for (int i = 0; i < 8; ++i) { ml += lo[i]; mi += im[i]; }
        ml *= 0.125f; mi *= 0.125f;
        float sl = 0.f, si = 0.f;
        #pragma unroll
        for (int i = 0; i < 8; ++i) {
            const float dl = lo[i] - ml, di = im[i] - mi;
            sl += dl * dl; si += di * di;
        }
        const float cvl = (sl / 7.f) / (ml * ml + 1e-10f);
        const float cvi = (si / 7.f) / (mi * mi + 1e-10f);
        out_scalars[0] = 0.01f * (cvi + cvl);
        out_scalars[1] = 0.0f;
    }
}

extern "C" void kernel_launch(void* const* d_in, const int* in_sizes, int n_in,
                              void* d_out, int out_size, void* d_ws, size_t ws_size,
                              hipStream_t stream)
{
    const float* x        = (const float*)d_in[0];
    // d_in[1] = x_mark_enc (unused)
    const float* noise    = (const float*)d_in[2];
    const float* start_w  = (const float*)d_in[3];
    const float* start_b  = (const float*)d_in[4];
    const float* w_gate   = (const float*)d_in[5];
    const float* w_noise  = (const float*)d_in[6];
    const float* expert_w = (const float*)d_in[7];
    const float* expert_b = (const float*)d_in[8];
    float* out            = (float*)d_out;

    float* accum = (float*)d_ws;                       // 16 floats
    u16*   wt    = (u16*)((char*)d_ws + 256);          // 8*96*320 bf16 = 480 KB

    hipMemsetAsync(accum, 0, 16 * sizeof(float), stream);
    hipLaunchKernelGGL(transpose_w, dim3(Ee, Lr / 32), dim3(256), 0, stream,
                       expert_w, wt);
    hipLaunchKernelGGL(fused_kernel, dim3(Bn), dim3(256), 0, stream,
                       x, noise, start_w, start_b, w_gate, w_noise,
                       wt, expert_b, accum, out);
    hipLaunchKernelGGL(loss_kernel, dim3(1), dim3(64), 0, stream,
                       accum, out + (size_t)Bn * Pp * Dd);
}

// Round 4
// 316.030 us; speedup vs baseline: 1.2593x; 1.0172x over previous
//
#include <hip/hip_runtime.h>
#include <hip/hip_bf16.h>

#define Bn 1024
#define Lr 320
#define Dd 128
#define Ee 8
#define Pp 96

typedef short bf16x8 __attribute__((ext_vector_type(8)));
typedef float f32x4 __attribute__((ext_vector_type(4)));
typedef unsigned short u16;

__device__ __forceinline__ float cdf_f(float v) {
    return 0.5f * (1.0f + erff(v * 0.70710678118654752f));
}
__device__ __forceinline__ float softplus_f(float x) {
    return fmaxf(x, 0.0f) + log1pf(expf(-fabsf(x)));
}
__device__ __forceinline__ u16 f2bf(float f) {
    unsigned int u = __float_as_uint(f);
    return (u16)((u + 0x7fffu + ((u >> 16) & 1u)) >> 16);
}
__device__ __forceinline__ float bf2f(u16 u) {
    return __uint_as_float(((unsigned int)u) << 16);
}

// expert_w fp32 [e][l][p] -> W_t bf16 [e][p][l] (l contiguous). 0.5 MB, L2-resident.
__global__ __launch_bounds__(256) void transpose_w(
    const float* __restrict__ ew, u16* __restrict__ wt)
{
    __shared__ float tile[Pp * 33];
    const int e  = blockIdx.x;       // 0..7
    const int l0 = blockIdx.y * 32;  // 0..288
    const int t  = threadIdx.x;
    #pragma unroll
    for (int i = 0; i < 12; ++i) {
        const int idx = t + 256 * i;            // 0..3071
        const int lp = idx / 96, p = idx - 96 * lp;
        tile[p * 33 + lp] = ew[((size_t)e * Lr + l0 + lp) * Pp + p];
    }
    __syncthreads();
    #pragma unroll
    for (int i = 0; i < 6; ++i) {
        const int g = t + 256 * i;              // 0..1535
        const int p = g >> 4, l2 = (g & 15) * 2;
        const unsigned pk = (unsigned)f2bf(tile[p * 33 + l2]) |
                            ((unsigned)f2bf(tile[p * 33 + l2 + 1]) << 16);
        *(unsigned*)&wt[((size_t)(e * Pp + p)) * Lr + l0 + l2] = pk;
    }
}

// K1a: g[b,l] = dot(x[b,l,:], start_w) + sb. Pure streaming HBM read of x.
// grid (5, 1024): block = (l-chunk of 64, b). 8 lanes per row, 2 rows/thread.
__global__ __launch_bounds__(256, 8) void g_kernel(
    const float* __restrict__ x, const float* __restrict__ start_w,
    const float* __restrict__ start_b, float* __restrict__ g_out)
{
    const int t  = threadIdx.x;
    const int lc = blockIdx.x;       // 0..4
    const int b  = blockIdx.y;       // 0..1023
    const float sb = start_b[0];

    float4 sw[4];
    #pragma unroll
    for (int j = 0; j < 4; ++j) sw[j] = ((const float4*)start_w)[(t & 7) + 8 * j];

    const float* xb = x + ((size_t)b * Lr + lc * 64) * Dd;
    #pragma unroll
    for (int p2 = 0; p2 < 2; ++p2) {
        const int r = p2 * 32 + (t >> 3);
        float acc = 0.f;
        #pragma unroll
        for (int j = 0; j < 4; ++j) {
            const float4 v = ((const float4*)(xb + (size_t)r * Dd))[(t & 7) + 8 * j];
            acc += v.x * sw[j].x + v.y * sw[j].y + v.z * sw[j].z + v.w * sw[j].w;
        }
        #pragma unroll
        for (int off = 1; off <= 4; off <<= 1) acc += __shfl_xor(acc, off);
        if ((t & 7) == 0) g_out[(size_t)b * Lr + lc * 64 + r] = acc + sb;
    }
}

// K1b: per-b logits, noisy top-3, gates, prob. One wave per b (4 b per block).
__global__ __launch_bounds__(256) void gate_kernel(
    const float* __restrict__ g, const float* __restrict__ noise,
    const float* __restrict__ w_gate, const float* __restrict__ w_noise,
    float* __restrict__ accum, float* __restrict__ gates_out)
{
    __shared__ float sred[16];
    const int t    = threadIdx.x;
    const int lane = t & 63;
    const int wv   = t >> 6;
    const int b    = blockIdx.x * 4 + wv;

    if (t < 16) sred[t] = 0.f;
    __syncthreads();

    const int e = lane & 7, seg = lane >> 3;
    const float* gb = g + (size_t)b * Lr;
    float pc = 0.f, pn = 0.f;
    #pragma unroll 8
    for (int i = 0; i < 40; ++i) {
        const int l = seg * 40 + i;
        const float gv = gb[l];
        pc += gv * w_gate[l * Ee + e];
        pn += gv * w_noise[l * Ee + e];
    }
    #pragma unroll
    for (int off = 8; off <= 32; off <<= 1) {
        pc += __shfl_xor(pc, off);
        pn += __shfl_xor(pn, off);
    }
    // every lane now holds totals for its e = lane&7
    const float sdv   = softplus_f(pn) + 0.01f;   // NOISE_EPS
    float       c     = pc;
    const float nz    = noise[b * Ee + e];
    const float noisy = c + nz * sdv;

    float nv[8];
    #pragma unroll
    for (int j = 0; j < 8; ++j) nv[j] = __shfl(noisy, j);

    int i0 = -1, i1 = -1;
    float v0 = -INFINITY, v1 = -INFINITY, v2 = -INFINITY;
    #pragma unroll
    for (int i = 0; i < 8; ++i) if (nv[i] > v0) { v0 = nv[i]; i0 = i; }
    #pragma unroll
    for (int i = 0; i < 8; ++i) if (i != i0 && nv[i] > v1) { v1 = nv[i]; i1 = i; }
    #pragma unroll
    for (int i = 0; i < 8; ++i) if (i != i0 && i != i1 && nv[i] > v2) { v2 = nv[i]; }

    const float ex1 = expf(v1 - v0);
    const float den = 1.f + ex1;
    const float gate_e = (e == i0) ? (1.f / den) : ((e == i1) ? (ex1 / den) : 0.f);

    if (isnan(c)) c = 0.f;
    const float pr = (noisy > v2) ? cdf_f((c - v2) / sdv) : cdf_f((c - v1) / sdv);

    if (lane < 8) {
        gates_out[b * Ee + e] = gate_e;
        atomicAdd(&sred[8 + e], gate_e);  // importance
        atomicAdd(&sred[e], pr);          // load
    }
    __syncthreads();
    if (t < 16) atomicAdd(&accum[t], sred[t]);
}

// K2: out[b][p][d-half] = sum_l (g0*W[e0]+g1*W[e1])[l,p] * x[b,l,d] via bf16 MFMA.
// grid 2048 = (b, d-half). Conflict-free LDS (stride 34 u16 = 17 dwords).
__global__ __launch_bounds__(256, 4) void mm_kernel(
    const float* __restrict__ x, const u16* __restrict__ wt,
    const float* __restrict__ expert_b, const float* __restrict__ gates,
    float* __restrict__ out)
{
    __shared__ __align__(16) u16 Xs[64 * 34];   // [d_loc][l'] stride 34
    __shared__ __align__(16) u16 Ws[Pp * 34];   // [p][l'] stride 34

    const int b   = blockIdx.x >> 1;
    const int h   = blockIdx.x & 1;              // d-half
    const int tid = threadIdx.x;
    const int lane = tid & 63;
    const int wv   = tid >> 6;                   // wave = n-tile (16 d)
    const int quad = lane >> 4;
    const int r16  = lane & 15;

    // top-2 experts
    int e0 = 0, e1 = 0; float g0 = 0.f, g1 = 0.f; int cnt = 0;
    #pragma unroll
    for (int e = 0; e < Ee; ++e) {
        const float gv = gates[b * Ee + e];
        if (gv != 0.f) {
            if (cnt == 0) { e0 = e; g0 = gv; }
            else if (cnt == 1) { e1 = e; g1 = gv; }
            ++cnt;
        }
    }

    f32x4 acc[6];
    #pragma unroll
    for (int m = 0; m < 6; ++m) acc[m] = (f32x4){0.f, 0.f, 0.f, 0.f};

    const float* xb = x + (size_t)b * Lr * Dd + h * 64;
    const int dloc = tid & 63;       // staging: d column
    const int lg   = tid >> 6;       // l-group of 8

    for (int l0 = 0; l0 < Lr; l0 += 32) {
        // stage W tile: 96 p x 32 l, combined g0*wt[e0]+g1*wt[e1]
        #pragma unroll
        for (int i = 0; i < 3; ++i) {
            const int gi = tid + 256 * i;        // 0..767
            const int p = gi >> 3, lq = (gi & 7) * 4;
            const ushort4 w0 = *(const ushort4*)&wt[(size_t)(e0 * Pp + p) * Lr + l0 + lq];
            const ushort4 w1 = *(const ushort4*)&wt[(size_t)(e1 * Pp + p) * Lr + l0 + lq];
            const unsigned lo = (unsigned)f2bf(g0 * bf2f(w0.x) + g1 * bf2f(w1.x)) |
                                ((unsigned)f2bf(g0 * bf2f(w0.y) + g1 * bf2f(w1.y)) << 16);
            const unsigned hi = (unsigned)f2bf(g0 * bf2f(w0.z) + g1 * bf2f(w1.z)) |
                                ((unsigned)f2bf(g0 * bf2f(w0.w) + g1 * bf2f(w1.w)) << 16);
            ((unsigned*)Ws)[p * 17 + (lq >> 1)]     = lo;
            ((unsigned*)Ws)[p * 17 + (lq >> 1) + 1] = hi;
        }
        // stage x^T tile: 64 d x 32 l, scalar coalesced reads, paired b32 writes
        {
            float v[8];
            #pragma unroll
            for (int k = 0; k < 8; ++k)
                v[k] = xb[(size_t)(l0 + lg * 8 + k) * Dd + dloc];
            #pragma unroll
            for (int k2 = 0; k2 < 4; ++k2) {
                const unsigned pk = (unsigned)f2bf(v[2 * k2]) |
                                    ((unsigned)f2bf(v[2 * k2 + 1]) << 16);
                ((unsigned*)Xs)[dloc * 17 + lg * 4 + k2] = pk;
            }
        }
        __syncthreads();
        // fragments: lane-stride 17 dwords -> conflict-free b32 reads
        union U { unsigned u[4]; bf16x8 v; };
        U bfr;
        #pragma unroll
        for (int cW = 0; cW < 4; ++cW)
            bfr.u[cW] = ((const unsigned*)Xs)[(16 * wv + r16) * 17 + 4 * quad + cW];
        #pragma unroll
        for (int m = 0; m < 6; ++m) {
            U af;
            #pragma unroll
            for (int cW = 0; cW < 4; ++cW)
                af.u[cW] = ((const unsigned*)Ws)[(16 * m + r16) * 17 + 4 * quad + cW];
            acc[m] = __builtin_amdgcn_mfma_f32_16x16x32_bf16(af.v, bfr.v, acc[m], 0, 0, 0);
        }
        __syncthreads();
    }

    // epilogue: + g0*eb0 + g1*eb1; C/D layout: col(d)=r16, row(p)=4*quad+reg
    const int d = h * 64 + 16 * wv + r16;
    const float* eb0 = expert_b + (size_t)e0 * Pp * Dd;
    const float* eb1 = expert_b + (size_t)e1 * Pp * Dd;
    #pragma unroll
    for (int m = 0; m < 6; ++m) {
        #pragma unroll
        for (int r = 0; r < 4; ++r) {
            const int p = 16 * m + 4 * quad + r;
            out[((size_t)b * Pp + p) * Dd + d] =
                acc[m][r] + g0 * eb0[p * Dd + d] + g1 * eb1[p * Dd + d];
        }
    }
}

__global__ void loss_kernel(const float* __restrict__ accum,
                            float* __restrict__ out_scalars)
{
    if (threadIdx.x == 0) {
        float lo[8], im[8];
        #pragma unroll
        for (int i = 0; i < 8; ++i) { lo[i] = accum[i]; im[i] = accum[8 + i]; }
        float ml = 0.f, mi = 0.f;
        #pragma unroll
        for (int i = 0; i < 8; ++i) { ml += lo[i]; mi += im[i]; }
        ml *= 0.125f; mi *= 0.125f;
        float sl = 0.f, si = 0.f;
        #pragma unroll
        for (int i = 0; i < 8; ++i) {
            const float dl = lo[i] - ml, di = im[i] - mi;
            sl += dl * dl; si += di * di;
        }
        const float cvl = (sl / 7.f) / (ml * ml + 1e-10f);
        const float cvi = (si / 7.f) / (mi * mi + 1e-10f);
        out_scalars[0] = 0.01f * (cvi + cvl);
        out_scalars[1] = 0.0f;
    }
}

extern "C" void kernel_launch(void* const* d_in, const int* in_sizes, int n_in,
                              void* d_out, int out_size, void* d_ws, size_t ws_size,
                              hipStream_t stream)
{
    const float* x        = (const float*)d_in[0];
    // d_in[1] = x_mark_enc (unused)
    const float* noise    = (const float*)d_in[2];
    const float* start_w  = (const float*)d_in[3];
    const float* start_b  = (const float*)d_in[4];
    const float* w_gate   = (const float*)d_in[5];
    const float* w_noise  = (const float*)d_in[6];
    const float* expert_w = (const float*)d_in[7];
    const float* expert_b = (const float*)d_in[8];
    float* out            = (float*)d_out;

    float* accum = (float*)d_ws;                 // 16 f
    float* gates = accum + 16;                   // 8192 f
    float* gbuf  = gates + Bn * Ee;              // 1024*320 f
    u16*   wt    = (u16*)(gbuf + Bn * Lr);       // 8*96*320 bf16

    hipMemsetAsync(accum, 0, 16 * sizeof(float), stream);
    hipLaunchKernelGGL(transpose_w, dim3(Ee, Lr / 32), dim3(256), 0, stream,
                       expert_w, wt);
    hipLaunchKernelGGL(g_kernel, dim3(5, Bn), dim3(256), 0, stream,
                       x, start_w, start_b, gbuf);
    hipLaunchKernelGGL(gate_kernel, dim3(Bn / 4), dim3(256), 0, stream,
                       gbuf, noise, w_gate, w_noise, accum, gates);
    hipLaunchKernelGGL(mm_kernel, dim3(Bn * 2), dim3(256), 0, stream,
                       x, wt, expert_b, gates, out);
    hipLaunchKernelGGL(loss_kernel, dim3(1), dim3(64), 0, stream,
                       accum, out + (size_t)Bn * Pp * Dd);
}